// Round 3
// baseline (199.135 us; speedup 1.0000x reference)
//
#include <hip/hip_runtime.h>

// PureQNet restructured: the depth-6 4-qubit circuit is input-independent, so
// precompute its 16x16 unitary (K0, one block) and reduce the per-image work
// (K1) to: pool -> two 16-wide matvecs -> probs -> 10x16 head matvec.
//
// ws float layout: [0,256) Ure, [256,512) Uim, [512,672) M2 (10x16).

#define QNET_NQ 4
#define QNET_DEPTH 6

__global__ __launch_bounds__(256) void qnet_tables(
    const float* __restrict__ qw,       // (6,4)
    const float* __restrict__ head_w,   // (10,10)
    float* __restrict__ tab)            // ws
{
    const int t   = threadIdx.x;
    const int k   = t >> 4;             // basis-state column
    const int idx = t & 15;             // amplitude index (wire0 = MSB)

    // evolve basis state k through the circuit (xor masks <16 stay in-group)
    float re = (idx == k) ? 1.f : 0.f;
    float im = 0.f;
#pragma unroll
    for (int l = 0; l < QNET_DEPTH; ++l) {
#pragma unroll
        for (int q = 0; q < QNET_NQ; ++q) {
            const float half = 0.5f * qw[l * QNET_NQ + q];
            float sn, cs;
            sincosf(half, &sn, &cs);
            const int bit = 1 << (3 - q);
            const float re_p = __shfl_xor(re, bit);
            const float im_p = __shfl_xor(im, bit);
            re = cs * re + sn * im_p;   // RX: new = c*self - i*s*partner
            im = cs * im - sn * re_p;
        }
#pragma unroll
        for (int q = 0; q < QNET_NQ; ++q) {          // CNOT(q -> (q+1)%4)
            const int cb = 1 << (3 - q);
            const int tb = 1 << (3 - ((q + 1) & 3));
            const float re_s = __shfl_xor(re, tb);
            const float im_s = __shfl_xor(im, tb);
            const bool ctrl = (idx & cb) != 0;
            re = ctrl ? re_s : re;
            im = ctrl ? im_s : im;
        }
    }
    tab[idx * 16 + k]       = re;       // Ure[row][col]
    tab[256 + idx * 16 + k] = im;       // Uim[row][col]

    // M2[r][j] = sum_k head_w[r][k] * Zsign_k(j)
    if (t < 160) {
        const int r = t >> 4, j = t & 15;
        const float z0 = (j & 8) ? -1.f : 1.f;
        const float z1 = (j & 4) ? -1.f : 1.f;
        const float z2 = (j & 2) ? -1.f : 1.f;
        const float z3 = (j & 1) ? -1.f : 1.f;
        const float* hw = head_w + r * 10;
        tab[512 + t] = z0 * hw[0] + z1 * hw[1] + z2 * hw[2] + z3 * hw[3]
                     + (z0 * z1) * hw[4] + (z0 * z2) * hw[5] + (z0 * z3) * hw[6]
                     + (z1 * z2) * hw[7] + (z1 * z3) * hw[8] + (z2 * z3) * hw[9];
    }
}

__global__ __launch_bounds__(256) void qnet_main(
    const float* __restrict__ x,        // (B,1,64,64)
    const float* __restrict__ tab,      // ws tables from qnet_tables
    const float* __restrict__ head_b,   // (10,)
    const float* __restrict__ scale,    // (1,)
    float* __restrict__ out)            // (B,10)
{
    __shared__ float pooled[16];
    __shared__ float ltab[672];

    const int b    = blockIdx.x;
    const int t    = threadIdx.x;
    const int wave = t >> 6;
    const int lane = t & 63;

    // stage tables into LDS (overlaps with pooling's memory latency)
    for (int i = t; i < 672; i += 256) ltab[i] = tab[i];

    // ---- adaptive avg pool to 4x4: wave w owns image rows [16w,16w+16) ----
    const float* img = x + (size_t)b * 4096 + (size_t)wave * 1024;
    float s = 0.f;
#pragma unroll
    for (int i = 0; i < 4; ++i) {
        float4 v = *reinterpret_cast<const float4*>(img + 4 * (lane + 64 * i));
        s += v.x + v.y + v.z + v.w;
    }
    s += __shfl_xor(s, 32);
    s += __shfl_xor(s, 16);
    s += __shfl_xor(s, 2);
    s += __shfl_xor(s, 1);
    if (lane < 16 && (lane & 3) == 0)
        pooled[wave * 4 + (lane >> 2)] = s * (1.0f / 256.0f);
    __syncthreads();

    if (wave != 0) return;  // wave 0 finishes the image (short tail now)

    // ---- psi[j] = sum_k U[j][k]*v[k]; prob = |psi|^2 / sum v^2 ----
    const int j = lane & 15;            // lanes 16-63 compute redundant copies
    float sre = 0.f, sim = 0.f, n2 = 0.f;
#pragma unroll
    for (int k = 0; k < 16; ++k) {
        const float a = pooled[k];                  // LDS broadcast
        n2  = fmaf(a, a, n2);
        sre = fmaf(ltab[j * 16 + k], a, sre);
        sim = fmaf(ltab[256 + j * 16 + k], a, sim);
    }
    const float prob = (sre * sre + sim * sim) / n2;

    // ---- head: out[r] = (b[r] + sum_j M2[r][j]*prob[j]) * scale ----
    const int r = (lane < 10) ? lane : 0;
    float acc = 0.f;
#pragma unroll
    for (int jj = 0; jj < 16; ++jj) {
        const float p = __shfl(prob, jj);           // prob of row jj
        acc = fmaf(ltab[512 + r * 16 + jj], p, acc);
    }
    if (lane < 10)
        out[(size_t)b * 10 + lane] = (head_b[lane] + acc) * scale[0];
}

extern "C" void kernel_launch(void* const* d_in, const int* in_sizes, int n_in,
                              void* d_out, int out_size, void* d_ws, size_t ws_size,
                              hipStream_t stream) {
    const float* x      = (const float*)d_in[0];
    const float* qw     = (const float*)d_in[1];
    const float* head_w = (const float*)d_in[2];
    const float* head_b = (const float*)d_in[3];
    const float* scale  = (const float*)d_in[4];
    float* out = (float*)d_out;
    float* tab = (float*)d_ws;

    const int B = in_sizes[0] / 4096;   // 8192

    qnet_tables<<<1, 256, 0, stream>>>(qw, head_w, tab);
    qnet_main<<<B, 256, 0, stream>>>(x, tab, head_b, scale, out);
}